// Round 6
// baseline (789.385 us; speedup 1.0000x reference)
//
#include <hip/hip_runtime.h>
#include <hip/hip_bf16.h>

#define TT 4096
#define BB 256
#define DD 3
#define UU 8

// ---------- fast activations ----------
#if defined(__has_builtin)
#if __has_builtin(__builtin_amdgcn_exp2f) && __has_builtin(__builtin_amdgcn_rcpf)
#define FAST_EXP2(x) __builtin_amdgcn_exp2f(x)
#define FAST_RCP(x)  __builtin_amdgcn_rcpf(x)
#endif
#endif
#ifndef FAST_EXP2
#define FAST_EXP2(x) exp2f(x)
#define FAST_RCP(x)  (1.0f / (x))
#endif

// scale constants folded into weights: sigmoid(x)=rcp(1+exp2(KI*x)), tanh(y)=1-2*rcp(1+exp2(KC*y))
#define KI (-1.4426950408889634f)   // -1/ln2
#define KC (2.8853900817779268f)    // 2/ln2

__device__ __forceinline__ float fsig(float x) {
    float e = FAST_EXP2(KI * x);
    return FAST_RCP(1.0f + e);
}
__device__ __forceinline__ float ftanh(float x) {
    float e = FAST_EXP2(KC * x);
    return 1.0f - 2.0f * FAST_RCP(1.0f + e);
}

// ---------- pure-VALU cross-lane via DPP ----------
// quad_perm xor1=0xB1, xor2=0x4E, xor3=0x1B; row_half_mirror(0x141)=xor7 within 8;
// row_ror:8 (0x128) = rotate by 8 within row16 == xor8 (rotation by half the row).
template <int CTRL>
__device__ __forceinline__ float dpp_f(float v) {
    int i = __builtin_bit_cast(int, v);
    i = __builtin_amdgcn_update_dpp(0, i, CTRL, 0xF, 0xF, true);
    return __builtin_bit_cast(float, i);
}

// ---------- cross-half sum: v[lane] + v[lane^32] ----------
// VERIFIED PRIMITIVE ONLY: plain __shfl_xor (compiler-lowered, unambiguous).
// permlane32_swap produced bit-identical wrong results across two different
// usage patterns (rounds 4/5) — abandoned until its semantics can be probed.
__device__ __forceinline__ float xswap_sum(float v) {
    return v + __shfl_xor(v, 32, 64);
}

// ---------- block-wide exclusive scan over 256 threads (verified, rounds 0-2) ----------
__device__ __forceinline__ float block_excl_scan(float v, int tid, float* red) {
    float x = v;
    int lid = tid & 63;
    #pragma unroll
    for (int d = 1; d < 64; d <<= 1) {
        float y = __shfl_up(x, d, 64);
        if (lid >= d) x += y;
    }
    int wave = tid >> 6;
    __syncthreads();
    if (lid == 63) red[wave] = x;
    __syncthreads();
    float off = 0.0f;
    for (int w = 0; w < wave; ++w) off += red[w];
    return off + (x - v);
}

// ---------- Kernel A: signature + gate precompute ----------
// ws layout: [t][b][32] floats: [0:8)=KI*i_pre, [8:16)=KC*c_pre, [16:24)=KI*o_pre,
// [24:32)=KI*f_logit (PRE-sigmoid, so kernel B applies one uniform sigmoid path).
// Scan structure is the verified sequential block_excl_scan from the passing kernels.
__global__ __launch_bounds__(256) void sig_pre_kernel(
    const float* __restrict__ x,     // (B,T,3)
    const float* __restrict__ Wi,    // (3,24)
    const float* __restrict__ Wf,    // (21,8)
    const float* __restrict__ bias,  // (32)
    float* __restrict__ ws)
{
    __shared__ float sWf[21 * 8];
    __shared__ float sWi[3 * 24];
    __shared__ float sB[32];
    __shared__ float red[4];

    const int tid = threadIdx.x;
    const int b = blockIdx.x;
    if (tid < 168) sWf[tid] = Wf[tid];
    if (tid < 72)  sWi[tid] = Wi[tid];
    if (tid < 32)  sB[tid]  = bias[tid];
    __syncthreads();

    const float dtc = 1.0f / 4095.0f;
    const int t0 = tid * 16;
    const float* xb = x + (size_t)b * TT * DD;

    float l1[4] = {0.f, 0.f, 0.f, 0.f};
    float l2[16];
    #pragma unroll
    for (int i = 0; i < 16; ++i) l2[i] = 0.f;
    {
        int s = (tid == 0) ? 1 : t0;
        float xp0 = xb[(s - 1) * 3 + 0];
        float xp1 = xb[(s - 1) * 3 + 1];
        float xp2 = xb[(s - 1) * 3 + 2];
        for (; s < t0 + 16; ++s) {
            float c0 = xb[s * 3 + 0], c1 = xb[s * 3 + 1], c2 = xb[s * 3 + 2];
            float dxv[4] = {dtc, c0 - xp0, c1 - xp1, c2 - xp2};
            #pragma unroll
            for (int r = 0; r < 4; ++r) {
                float tr = l1[r] + 0.5f * dxv[r];
                #pragma unroll
                for (int cc = 0; cc < 4; ++cc)
                    l2[r * 4 + cc] = fmaf(tr, dxv[cc], l2[r * 4 + cc]);
            }
            #pragma unroll
            for (int r = 0; r < 4; ++r) l1[r] += dxv[r];
            xp0 = c0; xp1 = c1; xp2 = c2;
        }
    }

    float S1[4], O1[4];
    #pragma unroll
    for (int r = 0; r < 4; ++r) { S1[r] = l1[r]; }
    for (int r = 0; r < 4; ++r) O1[r] = block_excl_scan(S1[r], tid, red);
    float O2[16];
    for (int rc = 0; rc < 16; ++rc) {
        float c2v = l2[rc] + O1[rc >> 2] * S1[rc & 3];
        O2[rc] = block_excl_scan(c2v, tid, red);
    }

    #pragma unroll
    for (int r = 0; r < 4; ++r) l1[r] = O1[r];
    #pragma unroll
    for (int i = 0; i < 16; ++i) l2[i] = O2[i];

    float xp0, xp1, xp2;
    {
        int tp = (tid == 0) ? 0 : (t0 - 1);
        xp0 = xb[tp * 3 + 0]; xp1 = xb[tp * 3 + 1]; xp2 = xb[tp * 3 + 2];
    }
    for (int i2 = 0; i2 < 16; ++i2) {
        const int t = t0 + i2;
        float c0 = xb[t * 3 + 0], c1 = xb[t * 3 + 1], c2 = xb[t * 3 + 2];
        if (t > 0) {
            float dxv[4] = {dtc, c0 - xp0, c1 - xp1, c2 - xp2};
            #pragma unroll
            for (int r = 0; r < 4; ++r) {
                float tr = l1[r] + 0.5f * dxv[r];
                #pragma unroll
                for (int cc = 0; cc < 4; ++cc)
                    l2[r * 4 + cc] = fmaf(tr, dxv[cc], l2[r * 4 + cc]);
            }
            #pragma unroll
            for (int r = 0; r < 4; ++r) l1[r] += dxv[r];
        }
        xp0 = c0; xp1 = c1; xp2 = c2;
        const float scale = (t == 0) ? 1.0f : (4095.0f / (float)t);
        float sg[21];
        sg[0] = scale;
        #pragma unroll
        for (int r = 0; r < 4; ++r) sg[1 + r] = l1[r] * scale;
        #pragma unroll
        for (int rc = 0; rc < 16; ++rc) sg[5 + rc] = l2[rc] * scale;

        float fa[8];
        #pragma unroll
        for (int u = 0; u < 8; ++u) fa[u] = sB[8 + u];
        #pragma unroll
        for (int j = 0; j < 21; ++j) {
            float s = sg[j];
            #pragma unroll
            for (int u = 0; u < 8; ++u) fa[u] = fmaf(s, sWf[j * 8 + u], fa[u]);
        }
        float g[24];
        #pragma unroll
        for (int u = 0; u < 8; ++u) {
            g[u] = sB[u]; g[8 + u] = sB[16 + u]; g[16 + u] = sB[24 + u];
        }
        #pragma unroll
        for (int gg = 0; gg < 24; ++gg) {
            g[gg] = fmaf(c0, sWi[gg], g[gg]);
            g[gg] = fmaf(c1, sWi[24 + gg], g[gg]);
            g[gg] = fmaf(c2, sWi[48 + gg], g[gg]);
        }
        float4* wp = (float4*)(ws + ((size_t)t * BB + b) * 32);
        wp[0] = make_float4(KI * g[0],  KI * g[1],  KI * g[2],  KI * g[3]);
        wp[1] = make_float4(KI * g[4],  KI * g[5],  KI * g[6],  KI * g[7]);
        wp[2] = make_float4(KC * g[8],  KC * g[9],  KC * g[10], KC * g[11]);
        wp[3] = make_float4(KC * g[12], KC * g[13], KC * g[14], KC * g[15]);
        wp[4] = make_float4(KI * g[16], KI * g[17], KI * g[18], KI * g[19]);
        wp[5] = make_float4(KI * g[20], KI * g[21], KI * g[22], KI * g[23]);
        wp[6] = make_float4(KI * fa[0], KI * fa[1], KI * fa[2], KI * fa[3]);
        wp[7] = make_float4(KI * fa[4], KI * fa[5], KI * fa[6], KI * fa[7]);
    }
}

// ---------- Kernel B: 32-lane-per-batch LSTM scan ----------
// Lane bits: u=0-2, gateLo=3, batch=4, gateHi=5. g=(gateHi,gateLo): 0=i,1=c,2=o,3=f.
// One exp2/rcp path covers all gates; cell update replicated per unit via
// row_ror:8 (i<->c, o<->f pairing, DPP) + __shfl_xor(32) cross-half combine.
// Only the g==0 octets store.
#define RING 8
__global__ __launch_bounds__(64) void lstm_scan_wide(
    const float* __restrict__ ws, const float* __restrict__ Wr,
    float* __restrict__ out)
{
    const int lane = threadIdx.x;
    const int u  = lane & 7;
    const int gl = (lane >> 3) & 1;
    const int q  = (lane >> 4) & 1;
    const int gh = (lane >> 5) & 1;
    const int g  = gh * 2 + gl;
    const int b  = blockIdx.x * 2 + q;
    const bool isC = (g == 1);
    const bool b3 = (gl != 0);
    const bool hiH = (gh != 0);
    const bool do_store = (g == 0);

    float wv[8];
    #pragma unroll
    for (int m = 0; m < 8; ++m) wv[m] = 0.0f;
    if (g != 3) {
        const float sc = isC ? KC : KI;
        #pragma unroll
        for (int m = 0; m < 8; ++m)
            wv[m] = sc * Wr[(u ^ m) * 24 + g * 8 + u];
    }
    const float Aact = isC ? (-2.0f * KC) : 1.0f;
    const float Bact = isC ? KC : 0.0f;

    const int comp = ((lane & 32) >> 1) | (lane & 15);   // g*8+u
    const float* gp = ws + (size_t)b * 32 + comp;        // + t*(BB*32)
    float* op = out + (size_t)b * TT * 8 + u;

    float buf[RING];
    #pragma unroll
    for (int p = 0; p < RING; ++p) buf[p] = gp[(size_t)p * (BB * 32)];

    float h = 0.0f, cs = 0.0f;   // cs = KC * cell[u], replicated across the 4 gate octets

    auto step = [&](int t, float pre) {
        // rotate h within each 8-lane octet (h replicated per octet)
        float h7 = dpp_f<0x141>(h);
        float h1 = dpp_f<0xB1>(h);
        float h2 = dpp_f<0x4E>(h);
        float h3 = dpp_f<0x1B>(h);
        float h6 = dpp_f<0xB1>(h7);
        float h5 = dpp_f<0x4E>(h7);
        float h4 = dpp_f<0x1B>(h7);
        // per-lane dot: gate g, unit u (f-lanes: wv=0 -> pre passes through)
        float a0 = fmaf(h,  wv[0], pre), a1 = h7 * wv[7];
        a0 = fmaf(h1, wv[1], a0); a1 = fmaf(h6, wv[6], a1);
        a0 = fmaf(h2, wv[2], a0); a1 = fmaf(h5, wv[5], a1);
        a0 = fmaf(h3, wv[3], a0); a1 = fmaf(h4, wv[4], a1);
        float acc = a0 + a1;
        // one activation path for ALL gates
        float r = FAST_RCP(1.0f + FAST_EXP2(acc));
        float act = fmaf(Aact, r, Bact);     // i/o/f: sigmoid; c: KC*tanh
        // pair exchange: i<->c, o<->f (within row16)
        float x8 = dpp_f<0x128>(act);        // row_ror:8 == xor8 within row16
        float prod  = act * x8;              // iv*cv2, identical bits on i- and c-lanes
        float fsel  = b3 ? act : x8;         // fv on o/f lanes
        float ovsel = b3 ? x8  : act;        // ov on o/f lanes
        float w = fsel * cs;                 // f*cs on o/f lanes
        float send  = hiH ? w : prod;        // lo half: iv*cv2, hi half: f*cs
        float osend = hiH ? ovsel : 0.0f;
        cs = xswap_sum(send);                // f*cs + iv*cv2 per unit, replicated
        float o1 = xswap_sum(osend);         // ov + 0, replicated
        float r2 = FAST_RCP(1.0f + FAST_EXP2(cs));
        h = fmaf(-2.0f * o1, r2, o1);        // ov * tanh(cell), replicated
        if (do_store) op[(size_t)t * 8] = h; // one octet per batch stores
    };

    for (int tb = 0; tb + RING < TT; tb += RING) {
        #pragma unroll
        for (int j = 0; j < RING; ++j) {
            const int t = tb + j;
            float pre = buf[j];
            buf[j] = gp[(size_t)(t + RING) * (BB * 32)];
            step(t, pre);
        }
    }
    #pragma unroll
    for (int j = 0; j < RING; ++j) step(TT - RING + j, buf[j]);
}

// ---------- Fallback: no-scratch single kernel (exact, unchanged) ----------
__global__ __launch_bounds__(64) void lstm_scan_ultra(
    const float* __restrict__ x, const float* __restrict__ Wi,
    const float* __restrict__ Wr, const float* __restrict__ Wf,
    const float* __restrict__ bias, float* __restrict__ out)
{
    const int lane = threadIdx.x;
    const int u = lane & 7;
    const int q = lane >> 3;
    const int b = blockIdx.x * 8 + q;
    float wa[8], wb[8], wc[8];
    #pragma unroll
    for (int m = 0; m < 8; ++m) {
        int j = u ^ m;
        wa[m] = Wr[j * 24 + u];
        wb[m] = Wr[j * 24 + 8 + u];
        wc[m] = Wr[j * 24 + 16 + u];
    }
    float wia[3], wib[3], wic[3];
    #pragma unroll
    for (int k = 0; k < 3; ++k) {
        wia[k] = Wi[k * 24 + u];
        wib[k] = Wi[k * 24 + 8 + u];
        wic[k] = Wi[k * 24 + 16 + u];
    }
    float wf[21];
    #pragma unroll
    for (int j = 0; j < 21; ++j) wf[j] = Wf[j * 8 + u];
    const float bi = bias[u], bf = bias[8 + u], bc = bias[16 + u], bo = bias[24 + u];
    const float* xb = x + (size_t)b * TT * 3;
    float l1[4] = {0.f, 0.f, 0.f, 0.f};
    float l2[16];
    #pragma unroll
    for (int i = 0; i < 16; ++i) l2[i] = 0.f;
    float xp0 = xb[0], xp1 = xb[1], xp2 = xb[2];
    float h = 0.f, c = 0.f;
    float* op = out + (size_t)b * TT * 8 + u;
    const float dtc = 1.0f / 4095.0f;
    for (int t = 0; t < TT; ++t) {
        float c0 = xb[t * 3 + 0], c1 = xb[t * 3 + 1], c2 = xb[t * 3 + 2];
        if (t > 0) {
            float dxv[4] = {dtc, c0 - xp0, c1 - xp1, c2 - xp2};
            #pragma unroll
            for (int r = 0; r < 4; ++r) {
                float tr = l1[r] + 0.5f * dxv[r];
                #pragma unroll
                for (int cc = 0; cc < 4; ++cc)
                    l2[r * 4 + cc] = fmaf(tr, dxv[cc], l2[r * 4 + cc]);
            }
            #pragma unroll
            for (int r = 0; r < 4; ++r) l1[r] += dxv[r];
        }
        xp0 = c0; xp1 = c1; xp2 = c2;
        const float scale = (t == 0) ? 1.0f : (4095.0f / (float)t);
        float dot = wf[0];
        #pragma unroll
        for (int r = 0; r < 4; ++r) dot = fmaf(l1[r], wf[1 + r], dot);
        #pragma unroll
        for (int rc = 0; rc < 16; ++rc) dot = fmaf(l2[rc], wf[5 + rc], dot);
        float fv = fsig(fmaf(scale, dot, bf));
        float gi = bi, gc = bc, go = bo;
        gi = fmaf(c0, wia[0], gi); gi = fmaf(c1, wia[1], gi); gi = fmaf(c2, wia[2], gi);
        gc = fmaf(c0, wib[0], gc); gc = fmaf(c1, wib[1], gc); gc = fmaf(c2, wib[2], gc);
        go = fmaf(c0, wic[0], go); go = fmaf(c1, wic[1], go); go = fmaf(c2, wic[2], go);
        float h1 = dpp_f<0xB1>(h);
        float h2 = dpp_f<0x4E>(h);
        float h3 = dpp_f<0x1B>(h);
        float h7 = dpp_f<0x141>(h);
        float h6 = dpp_f<0xB1>(h7);
        float h5 = dpp_f<0x4E>(h7);
        float h4 = dpp_f<0x1B>(h7);
        gi = fmaf(h, wa[0], gi); gi = fmaf(h1, wa[1], gi); gi = fmaf(h2, wa[2], gi); gi = fmaf(h3, wa[3], gi);
        gi = fmaf(h4, wa[4], gi); gi = fmaf(h5, wa[5], gi); gi = fmaf(h6, wa[6], gi); gi = fmaf(h7, wa[7], gi);
        gc = fmaf(h, wb[0], gc); gc = fmaf(h1, wb[1], gc); gc = fmaf(h2, wb[2], gc); gc = fmaf(h3, wb[3], gc);
        gc = fmaf(h4, wb[4], gc); gc = fmaf(h5, wb[5], gc); gc = fmaf(h6, wb[6], gc); gc = fmaf(h7, wb[7], gc);
        go = fmaf(h, wc[0], go); go = fmaf(h1, wc[1], go); go = fmaf(h2, wc[2], go); go = fmaf(h3, wc[3], go);
        go = fmaf(h4, wc[4], go); go = fmaf(h5, wc[5], go); go = fmaf(h6, wc[6], go); go = fmaf(h7, wc[7], go);
        float iv = fsig(gi);
        float cv = ftanh(gc);
        float ov = fsig(go);
        c = fmaf(fv, c, iv * cv);
        h = ov * ftanh(c);
        op[(size_t)t * 8] = h;
    }
}

extern "C" void kernel_launch(void* const* d_in, const int* in_sizes, int n_in,
                              void* d_out, int out_size, void* d_ws, size_t ws_size,
                              hipStream_t stream) {
    const float* x    = (const float*)d_in[0];  // (256,4096,3)
    const float* Wi   = (const float*)d_in[1];  // (3,24)
    const float* Wr   = (const float*)d_in[2];  // (8,24)
    const float* Wf   = (const float*)d_in[3];  // (21,8)
    const float* bias = (const float*)d_in[4];  // (32,)
    float* out = (float*)d_out;                 // (256,4096,8)

    const size_t need = (size_t)TT * BB * 32 * sizeof(float);  // 128 MiB
    if (ws_size >= need) {
        sig_pre_kernel<<<dim3(BB), dim3(256), 0, stream>>>(x, Wi, Wf, bias, (float*)d_ws);
        lstm_scan_wide<<<dim3(BB / 2), dim3(64), 0, stream>>>((const float*)d_ws, Wr, out);
    } else {
        lstm_scan_ultra<<<dim3(BB / 8), dim3(64), 0, stream>>>(x, Wi, Wr, Wf, bias, out);
    }
}

// Round 7
// 788.032 us; speedup vs baseline: 1.0017x; 1.0017x over previous
//
#include <hip/hip_runtime.h>
#include <hip/hip_bf16.h>

#define TT 4096
#define BB 256
#define DD 3
#define UU 8

// ---------- fast activations ----------
#if defined(__has_builtin)
#if __has_builtin(__builtin_amdgcn_exp2f) && __has_builtin(__builtin_amdgcn_rcpf)
#define FAST_EXP2(x) __builtin_amdgcn_exp2f(x)
#define FAST_RCP(x)  __builtin_amdgcn_rcpf(x)
#endif
#if __has_builtin(__builtin_amdgcn_permlane32_swap)
#define HAVE_PL32 1
#endif
#endif
#ifndef FAST_EXP2
#define FAST_EXP2(x) exp2f(x)
#define FAST_RCP(x)  (1.0f / (x))
#endif

// scale constants folded into weights: sigmoid(x)=rcp(1+exp2(KI*x)), tanh(y)=1-2*rcp(1+exp2(KC*y))
#define KI (-1.4426950408889634f)   // -1/ln2
#define KC (2.8853900817779268f)    // 2/ln2

__device__ __forceinline__ float fsig(float x) {
    float e = FAST_EXP2(KI * x);
    return FAST_RCP(1.0f + e);
}
__device__ __forceinline__ float ftanh(float x) {
    float e = FAST_EXP2(KC * x);
    return 1.0f - 2.0f * FAST_RCP(1.0f + e);
}

// ---------- pure-VALU cross-lane via DPP ----------
template <int CTRL>
__device__ __forceinline__ float dpp_f(float v) {
    int i = __builtin_bit_cast(int, v);
    i = __builtin_amdgcn_update_dpp(0, i, CTRL, 0xF, 0xF, true);
    return __builtin_bit_cast(float, i);
}

// ---------- cross-half sum: v[lane] + v[lane^32] ----------
// FAST: v_permlane32_swap with a forced-distinct physical copy (early-clobber
// v_mov; both vregs live into the builtin -> distinct physical registers
// guaranteed). r[0]+r[1] is correct under either swap-diagonal convention.
// SEMANTICS ARE RUNTIME-PROBED in the kernel; on any mismatch we run the
// shfl_xor fallback loop (bit-identical to the passing round-6 kernel).
template <bool FAST>
__device__ __forceinline__ float xsum(float v) {
#ifdef HAVE_PL32
    if constexpr (FAST) {
        float vc;
        asm("v_mov_b32 %0, %1" : "=&v"(vc) : "v"(v));
        typedef unsigned int uv2 __attribute__((ext_vector_type(2)));
        uv2 r = __builtin_amdgcn_permlane32_swap(
            __builtin_bit_cast(unsigned int, v),
            __builtin_bit_cast(unsigned int, vc), false, false);
        return __builtin_bit_cast(float, r[0]) + __builtin_bit_cast(float, r[1]);
    }
#endif
    return v + __shfl_xor(v, 32, 64);
}

// ---------- block-wide exclusive scan over 256 threads (verified) ----------
__device__ __forceinline__ float block_excl_scan(float v, int tid, float* red) {
    float x = v;
    int lid = tid & 63;
    #pragma unroll
    for (int d = 1; d < 64; d <<= 1) {
        float y = __shfl_up(x, d, 64);
        if (lid >= d) x += y;
    }
    int wave = tid >> 6;
    __syncthreads();
    if (lid == 63) red[wave] = x;
    __syncthreads();
    float off = 0.0f;
    for (int w = 0; w < wave; ++w) off += red[w];
    return off + (x - v);
}

// ---------- Kernel A: signature + gate precompute (unchanged from passing r6) ----------
// ws layout: [t][b][32]: [0:8)=KI*i_pre, [8:16)=KC*c_pre, [16:24)=KI*o_pre, [24:32)=KI*f_logit
__global__ __launch_bounds__(256) void sig_pre_kernel(
    const float* __restrict__ x,     // (B,T,3)
    const float* __restrict__ Wi,    // (3,24)
    const float* __restrict__ Wf,    // (21,8)
    const float* __restrict__ bias,  // (32)
    float* __restrict__ ws)
{
    __shared__ float sWf[21 * 8];
    __shared__ float sWi[3 * 24];
    __shared__ float sB[32];
    __shared__ float red[4];

    const int tid = threadIdx.x;
    const int b = blockIdx.x;
    if (tid < 168) sWf[tid] = Wf[tid];
    if (tid < 72)  sWi[tid] = Wi[tid];
    if (tid < 32)  sB[tid]  = bias[tid];
    __syncthreads();

    const float dtc = 1.0f / 4095.0f;
    const int t0 = tid * 16;
    const float* xb = x + (size_t)b * TT * DD;

    float l1[4] = {0.f, 0.f, 0.f, 0.f};
    float l2[16];
    #pragma unroll
    for (int i = 0; i < 16; ++i) l2[i] = 0.f;
    {
        int s = (tid == 0) ? 1 : t0;
        float xp0 = xb[(s - 1) * 3 + 0];
        float xp1 = xb[(s - 1) * 3 + 1];
        float xp2 = xb[(s - 1) * 3 + 2];
        for (; s < t0 + 16; ++s) {
            float c0 = xb[s * 3 + 0], c1 = xb[s * 3 + 1], c2 = xb[s * 3 + 2];
            float dxv[4] = {dtc, c0 - xp0, c1 - xp1, c2 - xp2};
            #pragma unroll
            for (int r = 0; r < 4; ++r) {
                float tr = l1[r] + 0.5f * dxv[r];
                #pragma unroll
                for (int cc = 0; cc < 4; ++cc)
                    l2[r * 4 + cc] = fmaf(tr, dxv[cc], l2[r * 4 + cc]);
            }
            #pragma unroll
            for (int r = 0; r < 4; ++r) l1[r] += dxv[r];
            xp0 = c0; xp1 = c1; xp2 = c2;
        }
    }

    float S1[4], O1[4];
    #pragma unroll
    for (int r = 0; r < 4; ++r) { S1[r] = l1[r]; }
    for (int r = 0; r < 4; ++r) O1[r] = block_excl_scan(S1[r], tid, red);
    float O2[16];
    for (int rc = 0; rc < 16; ++rc) {
        float c2v = l2[rc] + O1[rc >> 2] * S1[rc & 3];
        O2[rc] = block_excl_scan(c2v, tid, red);
    }

    #pragma unroll
    for (int r = 0; r < 4; ++r) l1[r] = O1[r];
    #pragma unroll
    for (int i = 0; i < 16; ++i) l2[i] = O2[i];

    float xp0, xp1, xp2;
    {
        int tp = (tid == 0) ? 0 : (t0 - 1);
        xp0 = xb[tp * 3 + 0]; xp1 = xb[tp * 3 + 1]; xp2 = xb[tp * 3 + 2];
    }
    for (int i2 = 0; i2 < 16; ++i2) {
        const int t = t0 + i2;
        float c0 = xb[t * 3 + 0], c1 = xb[t * 3 + 1], c2 = xb[t * 3 + 2];
        if (t > 0) {
            float dxv[4] = {dtc, c0 - xp0, c1 - xp1, c2 - xp2};
            #pragma unroll
            for (int r = 0; r < 4; ++r) {
                float tr = l1[r] + 0.5f * dxv[r];
                #pragma unroll
                for (int cc = 0; cc < 4; ++cc)
                    l2[r * 4 + cc] = fmaf(tr, dxv[cc], l2[r * 4 + cc]);
            }
            #pragma unroll
            for (int r = 0; r < 4; ++r) l1[r] += dxv[r];
        }
        xp0 = c0; xp1 = c1; xp2 = c2;
        const float scale = (t == 0) ? 1.0f : (4095.0f / (float)t);
        float sg[21];
        sg[0] = scale;
        #pragma unroll
        for (int r = 0; r < 4; ++r) sg[1 + r] = l1[r] * scale;
        #pragma unroll
        for (int rc = 0; rc < 16; ++rc) sg[5 + rc] = l2[rc] * scale;

        float fa[8];
        #pragma unroll
        for (int u = 0; u < 8; ++u) fa[u] = sB[8 + u];
        #pragma unroll
        for (int j = 0; j < 21; ++j) {
            float s = sg[j];
            #pragma unroll
            for (int u = 0; u < 8; ++u) fa[u] = fmaf(s, sWf[j * 8 + u], fa[u]);
        }
        float g[24];
        #pragma unroll
        for (int u = 0; u < 8; ++u) {
            g[u] = sB[u]; g[8 + u] = sB[16 + u]; g[16 + u] = sB[24 + u];
        }
        #pragma unroll
        for (int gg = 0; gg < 24; ++gg) {
            g[gg] = fmaf(c0, sWi[gg], g[gg]);
            g[gg] = fmaf(c1, sWi[24 + gg], g[gg]);
            g[gg] = fmaf(c2, sWi[48 + gg], g[gg]);
        }
        float4* wp = (float4*)(ws + ((size_t)t * BB + b) * 32);
        wp[0] = make_float4(KI * g[0],  KI * g[1],  KI * g[2],  KI * g[3]);
        wp[1] = make_float4(KI * g[4],  KI * g[5],  KI * g[6],  KI * g[7]);
        wp[2] = make_float4(KC * g[8],  KC * g[9],  KC * g[10], KC * g[11]);
        wp[3] = make_float4(KC * g[12], KC * g[13], KC * g[14], KC * g[15]);
        wp[4] = make_float4(KI * g[16], KI * g[17], KI * g[18], KI * g[19]);
        wp[5] = make_float4(KI * g[20], KI * g[21], KI * g[22], KI * g[23]);
        wp[6] = make_float4(KI * fa[0], KI * fa[1], KI * fa[2], KI * fa[3]);
        wp[7] = make_float4(KI * fa[4], KI * fa[5], KI * fa[6], KI * fa[7]);
    }
}

// ---------- Kernel B: 32-lane-per-batch scan, probed fast/slow exchange ----------
#define RING 8
template <bool FAST>
__device__ __forceinline__ void scan_loop(
    const float* __restrict__ gp, float* __restrict__ op,
    const float* wv, float Aact, float Bact, bool b3, bool hiH, bool do_store)
{
    float buf[RING];
    #pragma unroll
    for (int p = 0; p < RING; ++p) buf[p] = gp[(size_t)p * (BB * 32)];

    float h = 0.0f, cs = 0.0f;   // cs = KC * cell[u], replicated across gate octets

    auto step = [&](int t, float pre) {
        float h7 = dpp_f<0x141>(h);
        float h1 = dpp_f<0xB1>(h);
        float h2 = dpp_f<0x4E>(h);
        float h3 = dpp_f<0x1B>(h);
        float h6 = dpp_f<0xB1>(h7);
        float h5 = dpp_f<0x4E>(h7);
        float h4 = dpp_f<0x1B>(h7);
        float a0 = fmaf(h,  wv[0], pre), a1 = h7 * wv[7];
        a0 = fmaf(h1, wv[1], a0); a1 = fmaf(h6, wv[6], a1);
        a0 = fmaf(h2, wv[2], a0); a1 = fmaf(h5, wv[5], a1);
        a0 = fmaf(h3, wv[3], a0); a1 = fmaf(h4, wv[4], a1);
        float acc = a0 + a1;
        float r = FAST_RCP(1.0f + FAST_EXP2(acc));
        float act = fmaf(Aact, r, Bact);     // i/o/f: sigmoid; c: KC*tanh
        float x8 = dpp_f<0x128>(act);        // row_ror:8 == xor8: i<->c, o<->f
        float prod  = act * x8;              // iv*cv2 (identical on i/c lanes)
        float fsel  = b3 ? act : x8;         // fv on o/f lanes
        float ovsel = b3 ? x8  : act;        // ov on o/f lanes
        float w = fsel * cs;                 // f*cs on o/f lanes
        float send  = hiH ? w : prod;
        float osend = hiH ? ovsel : 0.0f;
        cs = xsum<FAST>(send);               // f*cs + iv*cv2, replicated
        float o1 = xsum<FAST>(osend);        // ov, replicated
        float r2 = FAST_RCP(1.0f + FAST_EXP2(cs));
        h = fmaf(-2.0f * o1, r2, o1);        // ov * tanh(cell), replicated
        if (do_store) op[(size_t)t * 8] = h;
    };

    for (int tb = 0; tb + RING < TT; tb += RING) {
        #pragma unroll
        for (int j = 0; j < RING; ++j) {
            const int t = tb + j;
            float pre = buf[j];
            buf[j] = gp[(size_t)(t + RING) * (BB * 32)];
            step(t, pre);
        }
    }
    #pragma unroll
    for (int j = 0; j < RING; ++j) step(TT - RING + j, buf[j]);
}

__global__ __launch_bounds__(64) void lstm_scan_wide(
    const float* __restrict__ ws, const float* __restrict__ Wr,
    float* __restrict__ out)
{
    const int lane = threadIdx.x;
    const int u  = lane & 7;
    const int gl = (lane >> 3) & 1;
    const int q  = (lane >> 4) & 1;
    const int gh = (lane >> 5) & 1;
    const int g  = gh * 2 + gl;
    const int b  = blockIdx.x * 2 + q;
    const bool isC = (g == 1);
    const bool b3 = (gl != 0);
    const bool hiH = (gh != 0);
    const bool do_store = (g == 0);

    float wv[8];
    #pragma unroll
    for (int m = 0; m < 8; ++m) wv[m] = 0.0f;
    if (g != 3) {
        const float sc = isC ? KC : KI;
        #pragma unroll
        for (int m = 0; m < 8; ++m)
            wv[m] = sc * Wr[(u ^ m) * 24 + g * 8 + u];
    }
    const float Aact = isC ? (-2.0f * KC) : 1.0f;
    const float Bact = isC ? KC : 0.0f;

    const int comp = ((lane & 32) >> 1) | (lane & 15);   // g*8+u
    const float* gp = ws + (size_t)b * 32 + comp;        // + t*(BB*32)
    float* op = out + (size_t)b * TT * 8 + u;

    // ---- runtime semantics probe for the permlane fast path ----
    bool fast_ok = false;
#ifdef HAVE_PL32
    {
        float pv = (lane < 32) ? 1.0f : 2.0f;
        fast_ok = (__all(xsum<true>(pv) == 3.0f) != 0);
    }
#endif
    if (fast_ok) scan_loop<true >(gp, op, wv, Aact, Bact, b3, hiH, do_store);
    else         scan_loop<false>(gp, op, wv, Aact, Bact, b3, hiH, do_store);
}

// ---------- Fallback: no-scratch single kernel (exact, unchanged) ----------
__global__ __launch_bounds__(64) void lstm_scan_ultra(
    const float* __restrict__ x, const float* __restrict__ Wi,
    const float* __restrict__ Wr, const float* __restrict__ Wf,
    const float* __restrict__ bias, float* __restrict__ out)
{
    const int lane = threadIdx.x;
    const int u = lane & 7;
    const int q = lane >> 3;
    const int b = blockIdx.x * 8 + q;
    float wa[8], wb[8], wc[8];
    #pragma unroll
    for (int m = 0; m < 8; ++m) {
        int j = u ^ m;
        wa[m] = Wr[j * 24 + u];
        wb[m] = Wr[j * 24 + 8 + u];
        wc[m] = Wr[j * 24 + 16 + u];
    }
    float wia[3], wib[3], wic[3];
    #pragma unroll
    for (int k = 0; k < 3; ++k) {
        wia[k] = Wi[k * 24 + u];
        wib[k] = Wi[k * 24 + 8 + u];
        wic[k] = Wi[k * 24 + 16 + u];
    }
    float wf[21];
    #pragma unroll
    for (int j = 0; j < 21; ++j) wf[j] = Wf[j * 8 + u];
    const float bi = bias[u], bf = bias[8 + u], bc = bias[16 + u], bo = bias[24 + u];
    const float* xb = x + (size_t)b * TT * 3;
    float l1[4] = {0.f, 0.f, 0.f, 0.f};
    float l2[16];
    #pragma unroll
    for (int i = 0; i < 16; ++i) l2[i] = 0.f;
    float xp0 = xb[0], xp1 = xb[1], xp2 = xb[2];
    float h = 0.f, c = 0.f;
    float* op = out + (size_t)b * TT * 8 + u;
    const float dtc = 1.0f / 4095.0f;
    for (int t = 0; t < TT; ++t) {
        float c0 = xb[t * 3 + 0], c1 = xb[t * 3 + 1], c2 = xb[t * 3 + 2];
        if (t > 0) {
            float dxv[4] = {dtc, c0 - xp0, c1 - xp1, c2 - xp2};
            #pragma unroll
            for (int r = 0; r < 4; ++r) {
                float tr = l1[r] + 0.5f * dxv[r];
                #pragma unroll
                for (int cc = 0; cc < 4; ++cc)
                    l2[r * 4 + cc] = fmaf(tr, dxv[cc], l2[r * 4 + cc]);
            }
            #pragma unroll
            for (int r = 0; r < 4; ++r) l1[r] += dxv[r];
        }
        xp0 = c0; xp1 = c1; xp2 = c2;
        const float scale = (t == 0) ? 1.0f : (4095.0f / (float)t);
        float dot = wf[0];
        #pragma unroll
        for (int r = 0; r < 4; ++r) dot = fmaf(l1[r], wf[1 + r], dot);
        #pragma unroll
        for (int rc = 0; rc < 16; ++rc) dot = fmaf(l2[rc], wf[5 + rc], dot);
        float fv = fsig(fmaf(scale, dot, bf));
        float gi = bi, gc = bc, go = bo;
        gi = fmaf(c0, wia[0], gi); gi = fmaf(c1, wia[1], gi); gi = fmaf(c2, wia[2], gi);
        gc = fmaf(c0, wib[0], gc); gc = fmaf(c1, wib[1], gc); gc = fmaf(c2, wib[2], gc);
        go = fmaf(c0, wic[0], go); go = fmaf(c1, wic[1], go); go = fmaf(c2, wic[2], go);
        float h1 = dpp_f<0xB1>(h);
        float h2 = dpp_f<0x4E>(h);
        float h3 = dpp_f<0x1B>(h);
        float h7 = dpp_f<0x141>(h);
        float h6 = dpp_f<0xB1>(h7);
        float h5 = dpp_f<0x4E>(h7);
        float h4 = dpp_f<0x1B>(h7);
        gi = fmaf(h, wa[0], gi); gi = fmaf(h1, wa[1], gi); gi = fmaf(h2, wa[2], gi); gi = fmaf(h3, wa[3], gi);
        gi = fmaf(h4, wa[4], gi); gi = fmaf(h5, wa[5], gi); gi = fmaf(h6, wa[6], gi); gi = fmaf(h7, wa[7], gi);
        gc = fmaf(h, wb[0], gc); gc = fmaf(h1, wb[1], gc); gc = fmaf(h2, wb[2], gc); gc = fmaf(h3, wb[3], gc);
        gc = fmaf(h4, wb[4], gc); gc = fmaf(h5, wb[5], gc); gc = fmaf(h6, wb[6], gc); gc = fmaf(h7, wb[7], gc);
        go = fmaf(h, wc[0], go); go = fmaf(h1, wc[1], go); go = fmaf(h2, wc[2], go); go = fmaf(h3, wc[3], go);
        go = fmaf(h4, wc[4], go); go = fmaf(h5, wc[5], go); go = fmaf(h6, wc[6], go); go = fmaf(h7, wc[7], go);
        float iv = fsig(gi);
        float cv = ftanh(gc);
        float ov = fsig(go);
        c = fmaf(fv, c, iv * cv);
        h = ov * ftanh(c);
        op[(size_t)t * 8] = h;
    }
}

extern "C" void kernel_launch(void* const* d_in, const int* in_sizes, int n_in,
                              void* d_out, int out_size, void* d_ws, size_t ws_size,
                              hipStream_t stream) {
    const float* x    = (const float*)d_in[0];  // (256,4096,3)
    const float* Wi   = (const float*)d_in[1];  // (3,24)
    const float* Wr   = (const float*)d_in[2];  // (8,24)
    const float* Wf   = (const float*)d_in[3];  // (21,8)
    const float* bias = (const float*)d_in[4];  // (32,)
    float* out = (float*)d_out;                 // (256,4096,8)

    const size_t need = (size_t)TT * BB * 32 * sizeof(float);  // 128 MiB
    if (ws_size >= need) {
        sig_pre_kernel<<<dim3(BB), dim3(256), 0, stream>>>(x, Wi, Wf, bias, (float*)d_ws);
        lstm_scan_wide<<<dim3(BB / 2), dim3(64), 0, stream>>>((const float*)d_ws, Wr, out);
    } else {
        lstm_scan_ultra<<<dim3(BB / 8), dim3(64), 0, stream>>>(x, Wi, Wr, Wf, bias, out);
    }
}